// Round 5
// baseline (334.973 us; speedup 1.0000x reference)
//
#include <hip/hip_runtime.h>
#include <hip/hip_bf16.h>

#define NB 8
#define CIN 256
#define LL 4096
#define CQ 32
#define CV 256

typedef __attribute__((ext_vector_type(8))) short bf16x8;
typedef __attribute__((ext_vector_type(4))) float f32x4;

__device__ __forceinline__ unsigned short f2bf(float f) {
    union { __hip_bfloat16 h; unsigned short u; } c;
    c.h = __float2bfloat16(f);
    return c.u;
}
__device__ __forceinline__ unsigned int f2bf2(float a, float b) {
    union { __hip_bfloat162 h; unsigned int u; } c;
    float2 f; f.x = a; f.y = b;
    c.h = __float22bfloat162_rn(f);
    return c.u;
}

// ---------------- K0: cast weights to bf16; Wq pre-scaled by log2(e) -----------
__global__ __launch_bounds__(256) void k_wcast(
    const float* __restrict__ Wq, const float* __restrict__ Wk,
    const float* __restrict__ Wv, const float* __restrict__ Wo,
    unsigned short* __restrict__ Wb, unsigned short* __restrict__ Wob)
{
    const float LOG2E = 1.4426950408889634f;
    const int row = blockIdx.x, t = threadIdx.x;
    if (row < 320) {
        float val;
        if (row < 32)      val = Wq[row * 256 + t] * LOG2E;
        else if (row < 64) val = Wk[(row - 32) * 256 + t];
        else               val = Wv[(row - 64) * 256 + t];
        Wb[row * 256 + t] = f2bf(val);
    } else {
        const int r2 = row - 320;
        Wob[r2 * 256 + t] = f2bf(Wo[r2 * 256 + t]);
    }
}

// ---------------- K1: fused QKV projection, MFMA bf16, 8 waves -----------------
// grid (64, 8), 512 thr. Wave w: v rows [64+w*32, 64+w*32+32); waves 0-3 also
// qk tile rows [w*16, w*16+16). qk stored transposed: qkt[n][l][64].
__global__ __launch_bounds__(512) void k_qkv3(
    const float* __restrict__ x, const unsigned short* __restrict__ Wb,
    unsigned short* __restrict__ qkt, unsigned short* __restrict__ v)
{
    __shared__ unsigned short xlds[64][264];
    __shared__ unsigned short tr[64][72];
    const int n = blockIdx.y, l0 = blockIdx.x * 64, t = threadIdx.x;
    const int w = t >> 6, lane = t & 63, lid = lane & 15, quad = lane >> 4;

    #pragma unroll
    for (int part = 0; part < 4; part++) {
        const int cbase = part * 64 + w * 8;
        float tmp[8];
        #pragma unroll
        for (int cc = 0; cc < 8; cc++)
            tmp[cc] = x[((size_t)n * CIN + cbase + cc) * LL + l0 + lane];
        bf16x8 s;
        #pragma unroll
        for (int cc = 0; cc < 8; cc++) s[cc] = (short)f2bf(tmp[cc]);
        *(bf16x8*)&xlds[lane][cbase] = s;
    }
    __syncthreads();

    const f32x4 fzero = {0.f, 0.f, 0.f, 0.f};
    f32x4 acc[3][4];
    #pragma unroll
    for (int mt = 0; mt < 3; mt++)
        #pragma unroll
        for (int nt = 0; nt < 4; nt++) acc[mt][nt] = fzero;

    for (int k0 = 0; k0 < 256; k0 += 32) {
        bf16x8 bx[4];
        #pragma unroll
        for (int nt = 0; nt < 4; nt++)
            bx[nt] = *(const bf16x8*)&xlds[nt * 16 + lid][k0 + quad * 8];
        #pragma unroll
        for (int vt = 0; vt < 2; vt++) {
            const bf16x8 wa = *(const bf16x8*)&Wb[(64 + w * 32 + vt * 16 + lid) * 256 + k0 + quad * 8];
            #pragma unroll
            for (int nt = 0; nt < 4; nt++)
                acc[vt][nt] = __builtin_amdgcn_mfma_f32_16x16x32_bf16(wa, bx[nt], acc[vt][nt], 0, 0, 0);
        }
        if (w < 4) {
            const bf16x8 wa = *(const bf16x8*)&Wb[(w * 16 + lid) * 256 + k0 + quad * 8];
            #pragma unroll
            for (int nt = 0; nt < 4; nt++)
                acc[2][nt] = __builtin_amdgcn_mfma_f32_16x16x32_bf16(wa, bx[nt], acc[2][nt], 0, 0, 0);
        }
    }
    #pragma unroll
    for (int vt = 0; vt < 2; vt++)
        #pragma unroll
        for (int nt = 0; nt < 4; nt++)
            #pragma unroll
            for (int reg = 0; reg < 4; reg++) {
                const int vr = w * 32 + vt * 16 + quad * 4 + reg;
                v[((size_t)n * CV + vr) * LL + l0 + nt * 16 + lid] = f2bf(acc[vt][nt][reg]);
            }
    if (w < 4) {
        #pragma unroll
        for (int nt = 0; nt < 4; nt++)
            #pragma unroll
            for (int reg = 0; reg < 4; reg++)
                tr[nt * 16 + lid][w * 16 + quad * 4 + reg] = f2bf(acc[2][nt][reg]);
    }
    __syncthreads();
    {
        const int l = t >> 3, c = (t & 7) * 8;
        *(uint4*)&qkt[((size_t)n * LL + l0 + l) * 64 + c] = *(const uint4*)&tr[l][c];
    }
}

// ---------------- K2: lns[i] = -log2( sum_j 2^(e2_ij) ), 8 waves ---------------
// grid (64, 8), 512 thr. Wave w covers j = jt*512 + w*64, jt 0..7.
__global__ __launch_bounds__(512) void k_rowsum3(
    const unsigned short* __restrict__ qkt, float* __restrict__ lns)
{
    __shared__ float red[64];
    const int n = blockIdx.y, i0 = blockIdx.x * 64, t = threadIdx.x;
    const int w = t >> 6, lid = t & 15, quad = (t & 63) >> 4;
    if (t < 64) red[t] = 0.f;
    __syncthreads();

    bf16x8 aq[4];
    #pragma unroll
    for (int mt = 0; mt < 4; mt++)
        aq[mt] = *(const bf16x8*)&qkt[((size_t)n * LL + i0 + mt * 16 + lid) * 64 + quad * 8];

    const f32x4 fzero = {0.f, 0.f, 0.f, 0.f};
    float sums[4][4];
    #pragma unroll
    for (int mt = 0; mt < 4; mt++)
        #pragma unroll
        for (int reg = 0; reg < 4; reg++) sums[mt][reg] = 0.f;

    for (int jt = 0; jt < 8; jt++) {
        const int j0 = jt * 512 + w * 64;
        bf16x8 bk[4];
        #pragma unroll
        for (int nt = 0; nt < 4; nt++)
            bk[nt] = *(const bf16x8*)&qkt[((size_t)n * LL + j0 + nt * 16 + lid) * 64 + 32 + quad * 8];
        #pragma unroll
        for (int mt = 0; mt < 4; mt++)
            #pragma unroll
            for (int nt = 0; nt < 4; nt++) {
                f32x4 e = __builtin_amdgcn_mfma_f32_16x16x32_bf16(aq[mt], bk[nt], fzero, 0, 0, 0);
                sums[mt][0] += __builtin_amdgcn_exp2f(e[0]);
                sums[mt][1] += __builtin_amdgcn_exp2f(e[1]);
                sums[mt][2] += __builtin_amdgcn_exp2f(e[2]);
                sums[mt][3] += __builtin_amdgcn_exp2f(e[3]);
            }
    }
    #pragma unroll
    for (int mt = 0; mt < 4; mt++)
        #pragma unroll
        for (int reg = 0; reg < 4; reg++) {
            float s = sums[mt][reg];
            s += __shfl_xor(s, 1); s += __shfl_xor(s, 2);
            s += __shfl_xor(s, 4); s += __shfl_xor(s, 8);
            if (lid == 0) atomicAdd(&red[mt * 16 + quad * 4 + reg], s);
        }
    __syncthreads();
    if (t < 64) lns[(size_t)n * LL + i0 + t] = -__builtin_log2f(red[t]);
}

__device__ __forceinline__ void write_p(unsigned short (*pl)[128], const f32x4* e,
                                        int w, int lid, int quad, int xkey)
{
    const int chunk = (2 * w + (quad >> 1)) ^ xkey;
    #pragma unroll
    for (int nt = 0; nt < 4; nt++) {
        uint2 d;
        d.x = f2bf2(__builtin_amdgcn_exp2f(e[nt][0]), __builtin_amdgcn_exp2f(e[nt][1]));
        d.y = f2bf2(__builtin_amdgcn_exp2f(e[nt][2]), __builtin_amdgcn_exp2f(e[nt][3]));
        *(uint2*)&pl[nt * 16 + lid][chunk * 8 + (quad & 1) * 4] = d;
    }
}

// ---------------- K3: fused attention core + output projection ----------------
// grid (512) 1D, 512 thr (8 waves). n = bid&7 (XCD-locality), j-tile = bid>>3.
// i-chunk 128/iter, 32 iters. Wave: 16 E-rows, 32 V-rows (acc[2][4]).
// All global prefetches issued BEFORE the O-phase so the pre-barrier vmcnt(0)
// drain finds them already complete (the round-4 stall).
__global__ __launch_bounds__(512, 4) void k_attn5(
    const unsigned short* __restrict__ qkt, const unsigned short* __restrict__ v,
    const float* __restrict__ lns, const unsigned short* __restrict__ Wob,
    const float* __restrict__ gp, float* __restrict__ out)
{
    __shared__ unsigned short lraw[64 * 264];   // 33792 B: P dbuf (32KB) / olds
    unsigned short (*plds)[64][128] = (unsigned short (*)[64][128])lraw;
    unsigned short (*olds)[264] = (unsigned short (*)[264])lraw;

    const int bid = blockIdx.x;
    const int n = bid & 7, j0 = (bid >> 3) * 64, t = threadIdx.x;
    const int w = t >> 6, lane = t & 63, lid = lane & 15, quad = lane >> 4;
    const int xkey = lid & 7;

    const unsigned short* qrow = qkt + ((size_t)n * LL + w * 16 + lid) * 64 + quad * 8;
    const float* lrow = lns + (size_t)n * LL + w * 16 + quad * 4;
    const unsigned short* vrow = v + ((size_t)n * CV + w * 32 + lid) * LL + quad * 8;

    bf16x8 bk[4];
    #pragma unroll
    for (int nt = 0; nt < 4; nt++)
        bk[nt] = *(const bf16x8*)&qkt[((size_t)n * LL + j0 + nt * 16 + lid) * 64 + 32 + quad * 8];

    const f32x4 fzero = {0.f, 0.f, 0.f, 0.f};
    f32x4 acc[2][4];
    #pragma unroll
    for (int mt = 0; mt < 2; mt++)
        #pragma unroll
        for (int nt = 0; nt < 4; nt++) acc[mt][nt] = fzero;

    // ---- prologue ----
    bf16x8 aq = *(const bf16x8*)qrow;
    f32x4 lnsC = *(const f32x4*)lrow;
    {
        f32x4 e[4];
        #pragma unroll
        for (int nt = 0; nt < 4; nt++)
            e[nt] = __builtin_amdgcn_mfma_f32_16x16x32_bf16(aq, bk[nt], lnsC, 0, 0, 0);
        aq = *(const bf16x8*)(qrow + (size_t)128 * 64);
        lnsC = *(const f32x4*)(lrow + 128);
        write_p(plds[0], e, w, lid, quad, xkey);
    }
    bf16x8 av[8];   // [mt*4+h]
    #pragma unroll
    for (int mt = 0; mt < 2; mt++)
        #pragma unroll
        for (int h = 0; h < 4; h++)
            av[mt * 4 + h] = *(const bf16x8*)(vrow + (size_t)mt * 16 * LL + h * 32);
    __syncthreads();

    #pragma unroll 2
    for (int ic = 0; ic < 31; ic++) {
        const int cur = ic & 1;
        const size_t i0 = (size_t)ic * 128;
        // E for ic+1 (operands prefetched)
        f32x4 e2[4];
        #pragma unroll
        for (int nt = 0; nt < 4; nt++)
            e2[nt] = __builtin_amdgcn_mfma_f32_16x16x32_bf16(aq, bk[nt], lnsC, 0, 0, 0);
        // global prefetches for ic+1/ic+2 — issued EARLY so they complete
        // during the O-phase, not at the barrier drain
        bf16x8 avn[8];
        #pragma unroll
        for (int mt = 0; mt < 2; mt++)
            #pragma unroll
            for (int h = 0; h < 4; h++)
                avn[mt * 4 + h] = *(const bf16x8*)(vrow + (size_t)mt * 16 * LL + (i0 + 128) + h * 32);
        const size_t ipf = (ic < 30) ? (i0 + 256) : i0;
        aq = *(const bf16x8*)(qrow + ipf * 64);
        lnsC = *(const f32x4*)(lrow + ipf);
        // finish E: exp2 + pack + write P(ic+1)
        write_p(plds[cur ^ 1], e2, w, lid, quad, xkey);
        // O-phase on buf cur
        #pragma unroll
        for (int h = 0; h < 4; h++) {
            bf16x8 bp[4];
            #pragma unroll
            for (int nt = 0; nt < 4; nt++)
                bp[nt] = *(const bf16x8*)&plds[cur][nt * 16 + lid][((4 * h + quad) ^ xkey) * 8];
            #pragma unroll
            for (int mt = 0; mt < 2; mt++)
                #pragma unroll
                for (int nt = 0; nt < 4; nt++)
                    acc[mt][nt] = __builtin_amdgcn_mfma_f32_16x16x32_bf16(av[mt * 4 + h], bp[nt], acc[mt][nt], 0, 0, 0);
        }
        #pragma unroll
        for (int z = 0; z < 8; z++) av[z] = avn[z];
        __syncthreads();
    }
    // ---- final O-phase: ic=31, buf 1 ----
    #pragma unroll
    for (int h = 0; h < 4; h++) {
        bf16x8 bp[4];
        #pragma unroll
        for (int nt = 0; nt < 4; nt++)
            bp[nt] = *(const bf16x8*)&plds[1][nt * 16 + lid][((4 * h + quad) ^ xkey) * 8];
        #pragma unroll
        for (int mt = 0; mt < 2; mt++)
            #pragma unroll
            for (int nt = 0; nt < 4; nt++)
                acc[mt][nt] = __builtin_amdgcn_mfma_f32_16x16x32_bf16(av[mt * 4 + h], bp[nt], acc[mt][nt], 0, 0, 0);
    }
    __syncthreads();   // all P reads done; reuse LDS as olds

    // ---- epilogue: o-tile -> olds[j][v] ----
    #pragma unroll
    for (int mt = 0; mt < 2; mt++)
        #pragma unroll
        for (int nt = 0; nt < 4; nt++) {
            ushort4 s;
            s.x = f2bf(acc[mt][nt][0]); s.y = f2bf(acc[mt][nt][1]);
            s.z = f2bf(acc[mt][nt][2]); s.w = f2bf(acc[mt][nt][3]);
            *(ushort4*)&olds[nt * 16 + lid][w * 32 + mt * 16 + quad * 4] = s;
        }
    __syncthreads();
    // out rows [w*32, w*32+32) x 64 l
    f32x4 oacc[2][4];
    #pragma unroll
    for (int mt = 0; mt < 2; mt++)
        #pragma unroll
        for (int nt = 0; nt < 4; nt++) oacc[mt][nt] = fzero;
    for (int k0 = 0; k0 < 256; k0 += 32) {
        bf16x8 bo[4];
        #pragma unroll
        for (int nt = 0; nt < 4; nt++)
            bo[nt] = *(const bf16x8*)&olds[nt * 16 + lid][k0 + quad * 8];
        #pragma unroll
        for (int mt = 0; mt < 2; mt++) {
            const bf16x8 wa = *(const bf16x8*)&Wob[(w * 32 + mt * 16 + lid) * 256 + k0 + quad * 8];
            #pragma unroll
            for (int nt = 0; nt < 4; nt++)
                oacc[mt][nt] = __builtin_amdgcn_mfma_f32_16x16x32_bf16(wa, bo[nt], oacc[mt][nt], 0, 0, 0);
        }
    }
    const float g = *gp;
    #pragma unroll
    for (int mt = 0; mt < 2; mt++)
        #pragma unroll
        for (int nt = 0; nt < 4; nt++)
            #pragma unroll
            for (int reg = 0; reg < 4; reg++) {
                const int r = w * 32 + mt * 16 + quad * 4 + reg;
                out[((size_t)n * CIN + r) * LL + j0 + nt * 16 + lid] = g * oacc[mt][nt][reg];
            }
}

extern "C" void kernel_launch(void* const* d_in, const int* in_sizes, int n_in,
                              void* d_out, int out_size, void* d_ws, size_t ws_size,
                              hipStream_t stream) {
    const float* x     = (const float*)d_in[0];
    const float* Wq    = (const float*)d_in[1];
    const float* Wk    = (const float*)d_in[2];
    const float* Wv    = (const float*)d_in[3];
    const float* Wo    = (const float*)d_in[4];
    const float* gamma = (const float*)d_in[5];

    unsigned short* qkt = (unsigned short*)d_ws;              // 4 MB
    unsigned short* v   = qkt + (size_t)NB * LL * 64;         // 16 MB
    unsigned short* Wb  = v + (size_t)NB * CV * LL;           // 160 KB
    unsigned short* Wob = Wb + 320 * 256;                     // 128 KB
    float* lns          = (float*)(Wob + 256 * 256);          // 128 KB
    float* out = (float*)d_out;

    k_wcast  <<<dim3(576),   256, 0, stream>>>(Wq, Wk, Wv, Wo, Wb, Wob);
    k_qkv3   <<<dim3(64, 8), 512, 0, stream>>>(x, Wb, qkt, v);
    k_rowsum3<<<dim3(64, 8), 512, 0, stream>>>(qkt, lns);
    k_attn5  <<<dim3(512),   512, 0, stream>>>(qkt, v, lns, Wob, gamma, out);
}

// Round 6
// 265.632 us; speedup vs baseline: 1.2610x; 1.2610x over previous
//
#include <hip/hip_runtime.h>
#include <hip/hip_bf16.h>

#define NB 8
#define CIN 256
#define LL 4096
#define CQ 32
#define CV 256

typedef __attribute__((ext_vector_type(8))) short bf16x8;
typedef __attribute__((ext_vector_type(4))) float f32x4;

__device__ __forceinline__ unsigned short f2bf(float f) {
    union { __hip_bfloat16 h; unsigned short u; } c;
    c.h = __float2bfloat16(f);
    return c.u;
}
__device__ __forceinline__ unsigned int f2bf2(float a, float b) {
    union { __hip_bfloat162 h; unsigned int u; } c;
    float2 f; f.x = a; f.y = b;
    c.h = __float22bfloat162_rn(f);
    return c.u;
}

// ---------------- K0: cast weights to bf16; Wq pre-scaled by log2(e) -----------
__global__ __launch_bounds__(256) void k_wcast(
    const float* __restrict__ Wq, const float* __restrict__ Wk,
    const float* __restrict__ Wv, const float* __restrict__ Wo,
    unsigned short* __restrict__ Wb, unsigned short* __restrict__ Wob)
{
    const float LOG2E = 1.4426950408889634f;
    const int row = blockIdx.x, t = threadIdx.x;
    if (row < 320) {
        float val;
        if (row < 32)      val = Wq[row * 256 + t] * LOG2E;
        else if (row < 64) val = Wk[(row - 32) * 256 + t];
        else               val = Wv[(row - 64) * 256 + t];
        Wb[row * 256 + t] = f2bf(val);
    } else {
        const int r2 = row - 320;
        Wob[r2 * 256 + t] = f2bf(Wo[r2 * 256 + t]);
    }
}

// ---------------- K1: fused QKV projection, MFMA bf16, 8 waves -----------------
// grid (64, 8), 512 thr. Wave w: v rows [64+w*32, 64+w*32+32); waves 0-3 also
// qk tile rows [w*16, w*16+16). qk stored transposed: qkt[n][l][64].
__global__ __launch_bounds__(512) void k_qkv3(
    const float* __restrict__ x, const unsigned short* __restrict__ Wb,
    unsigned short* __restrict__ qkt, unsigned short* __restrict__ v)
{
    __shared__ unsigned short xlds[64][264];
    __shared__ unsigned short tr[64][72];
    const int n = blockIdx.y, l0 = blockIdx.x * 64, t = threadIdx.x;
    const int w = t >> 6, lane = t & 63, lid = lane & 15, quad = lane >> 4;

    #pragma unroll
    for (int part = 0; part < 4; part++) {
        const int cbase = part * 64 + w * 8;
        float tmp[8];
        #pragma unroll
        for (int cc = 0; cc < 8; cc++)
            tmp[cc] = x[((size_t)n * CIN + cbase + cc) * LL + l0 + lane];
        bf16x8 s;
        #pragma unroll
        for (int cc = 0; cc < 8; cc++) s[cc] = (short)f2bf(tmp[cc]);
        *(bf16x8*)&xlds[lane][cbase] = s;
    }
    __syncthreads();

    const f32x4 fzero = {0.f, 0.f, 0.f, 0.f};
    f32x4 acc[3][4];
    #pragma unroll
    for (int mt = 0; mt < 3; mt++)
        #pragma unroll
        for (int nt = 0; nt < 4; nt++) acc[mt][nt] = fzero;

    for (int k0 = 0; k0 < 256; k0 += 32) {
        bf16x8 bx[4];
        #pragma unroll
        for (int nt = 0; nt < 4; nt++)
            bx[nt] = *(const bf16x8*)&xlds[nt * 16 + lid][k0 + quad * 8];
        #pragma unroll
        for (int vt = 0; vt < 2; vt++) {
            const bf16x8 wa = *(const bf16x8*)&Wb[(64 + w * 32 + vt * 16 + lid) * 256 + k0 + quad * 8];
            #pragma unroll
            for (int nt = 0; nt < 4; nt++)
                acc[vt][nt] = __builtin_amdgcn_mfma_f32_16x16x32_bf16(wa, bx[nt], acc[vt][nt], 0, 0, 0);
        }
        if (w < 4) {
            const bf16x8 wa = *(const bf16x8*)&Wb[(w * 16 + lid) * 256 + k0 + quad * 8];
            #pragma unroll
            for (int nt = 0; nt < 4; nt++)
                acc[2][nt] = __builtin_amdgcn_mfma_f32_16x16x32_bf16(wa, bx[nt], acc[2][nt], 0, 0, 0);
        }
    }
    #pragma unroll
    for (int vt = 0; vt < 2; vt++)
        #pragma unroll
        for (int nt = 0; nt < 4; nt++)
            #pragma unroll
            for (int reg = 0; reg < 4; reg++) {
                const int vr = w * 32 + vt * 16 + quad * 4 + reg;
                v[((size_t)n * CV + vr) * LL + l0 + nt * 16 + lid] = f2bf(acc[vt][nt][reg]);
            }
    if (w < 4) {
        #pragma unroll
        for (int nt = 0; nt < 4; nt++)
            #pragma unroll
            for (int reg = 0; reg < 4; reg++)
                tr[nt * 16 + lid][w * 16 + quad * 4 + reg] = f2bf(acc[2][nt][reg]);
    }
    __syncthreads();
    {
        const int l = t >> 3, c = (t & 7) * 8;
        *(uint4*)&qkt[((size_t)n * LL + l0 + l) * 64 + c] = *(const uint4*)&tr[l][c];
    }
}

// ---------------- K2: lns[i] = -log2( sum_j 2^(e2_ij) ), 8 waves ---------------
// grid (64, 8), 512 thr. Wave w covers j = jt*512 + w*64, jt 0..7.
__global__ __launch_bounds__(512) void k_rowsum3(
    const unsigned short* __restrict__ qkt, float* __restrict__ lns)
{
    __shared__ float red[64];
    const int n = blockIdx.y, i0 = blockIdx.x * 64, t = threadIdx.x;
    const int w = t >> 6, lid = t & 15, quad = (t & 63) >> 4;
    if (t < 64) red[t] = 0.f;
    __syncthreads();

    bf16x8 aq[4];
    #pragma unroll
    for (int mt = 0; mt < 4; mt++)
        aq[mt] = *(const bf16x8*)&qkt[((size_t)n * LL + i0 + mt * 16 + lid) * 64 + quad * 8];

    const f32x4 fzero = {0.f, 0.f, 0.f, 0.f};
    float sums[4][4];
    #pragma unroll
    for (int mt = 0; mt < 4; mt++)
        #pragma unroll
        for (int reg = 0; reg < 4; reg++) sums[mt][reg] = 0.f;

    for (int jt = 0; jt < 8; jt++) {
        const int j0 = jt * 512 + w * 64;
        bf16x8 bk[4];
        #pragma unroll
        for (int nt = 0; nt < 4; nt++)
            bk[nt] = *(const bf16x8*)&qkt[((size_t)n * LL + j0 + nt * 16 + lid) * 64 + 32 + quad * 8];
        #pragma unroll
        for (int mt = 0; mt < 4; mt++)
            #pragma unroll
            for (int nt = 0; nt < 4; nt++) {
                f32x4 e = __builtin_amdgcn_mfma_f32_16x16x32_bf16(aq[mt], bk[nt], fzero, 0, 0, 0);
                sums[mt][0] += __builtin_amdgcn_exp2f(e[0]);
                sums[mt][1] += __builtin_amdgcn_exp2f(e[1]);
                sums[mt][2] += __builtin_amdgcn_exp2f(e[2]);
                sums[mt][3] += __builtin_amdgcn_exp2f(e[3]);
            }
    }
    #pragma unroll
    for (int mt = 0; mt < 4; mt++)
        #pragma unroll
        for (int reg = 0; reg < 4; reg++) {
            float s = sums[mt][reg];
            s += __shfl_xor(s, 1); s += __shfl_xor(s, 2);
            s += __shfl_xor(s, 4); s += __shfl_xor(s, 8);
            if (lid == 0) atomicAdd(&red[mt * 16 + quad * 4 + reg], s);
        }
    __syncthreads();
    if (t < 64) lns[(size_t)n * LL + i0 + t] = -__builtin_log2f(red[t]);
}

__device__ __forceinline__ void write_p(unsigned short (*pl)[128], const f32x4* e,
                                        int w, int lid, int quad, int xkey)
{
    const int chunk = (2 * w + (quad >> 1)) ^ xkey;
    #pragma unroll
    for (int nt = 0; nt < 4; nt++) {
        uint2 d;
        d.x = f2bf2(__builtin_amdgcn_exp2f(e[nt][0]), __builtin_amdgcn_exp2f(e[nt][1]));
        d.y = f2bf2(__builtin_amdgcn_exp2f(e[nt][2]), __builtin_amdgcn_exp2f(e[nt][3]));
        *(uint2*)&pl[nt * 16 + lid][chunk * 8 + (quad & 1) * 4] = d;
    }
}

// ---------------- K3: fused attention core + output projection ----------------
// grid (512) 1D, 512 thr (8 waves). n = bid&7 (XCD-locality), j-tile = bid>>3.
// i-chunk 128/iter, 32 iters. Wave: 16 E-rows, 32 V-rows (acc[2][4]).
// av reloads are IN-PLACE (no extra regs — round 5's avn[] spilled to scratch)
// and staggered through the O-phase so the barrier's vmcnt(0) drain finds
// them already complete.
__global__ __launch_bounds__(512, 4) void k_attn6(
    const unsigned short* __restrict__ qkt, const unsigned short* __restrict__ v,
    const float* __restrict__ lns, const unsigned short* __restrict__ Wob,
    const float* __restrict__ gp, float* __restrict__ out)
{
    __shared__ unsigned short lraw[64 * 264];   // 33792 B: P dbuf (32KB) / olds
    unsigned short (*plds)[64][128] = (unsigned short (*)[64][128])lraw;
    unsigned short (*olds)[264] = (unsigned short (*)[264])lraw;

    const int bid = blockIdx.x;
    const int n = bid & 7, j0 = (bid >> 3) * 64, t = threadIdx.x;
    const int w = t >> 6, lane = t & 63, lid = lane & 15, quad = lane >> 4;
    const int xkey = lid & 7;

    const unsigned short* qrow = qkt + ((size_t)n * LL + w * 16 + lid) * 64 + quad * 8;
    const float* lrow = lns + (size_t)n * LL + w * 16 + quad * 4;
    const unsigned short* vrow = v + ((size_t)n * CV + w * 32 + lid) * LL + quad * 8;

    bf16x8 bk[4];
    #pragma unroll
    for (int nt = 0; nt < 4; nt++)
        bk[nt] = *(const bf16x8*)&qkt[((size_t)n * LL + j0 + nt * 16 + lid) * 64 + 32 + quad * 8];

    const f32x4 fzero = {0.f, 0.f, 0.f, 0.f};
    f32x4 acc[2][4];
    #pragma unroll
    for (int mt = 0; mt < 2; mt++)
        #pragma unroll
        for (int nt = 0; nt < 4; nt++) acc[mt][nt] = fzero;

    // ---- prologue ----
    bf16x8 aq = *(const bf16x8*)qrow;
    f32x4 lnsC = *(const f32x4*)lrow;
    {
        f32x4 e[4];
        #pragma unroll
        for (int nt = 0; nt < 4; nt++)
            e[nt] = __builtin_amdgcn_mfma_f32_16x16x32_bf16(aq, bk[nt], lnsC, 0, 0, 0);
        aq = *(const bf16x8*)(qrow + (size_t)128 * 64);
        lnsC = *(const f32x4*)(lrow + 128);
        write_p(plds[0], e, w, lid, quad, xkey);
    }
    bf16x8 av[8];   // [mt*4+h]
    #pragma unroll
    for (int mt = 0; mt < 2; mt++)
        #pragma unroll
        for (int h = 0; h < 4; h++)
            av[mt * 4 + h] = *(const bf16x8*)(vrow + (size_t)mt * 16 * LL + h * 32);
    __syncthreads();

    for (int ic = 0; ic < 31; ic++) {
        const int cur = ic & 1;
        const size_t i0 = (size_t)ic * 128;
        // E for ic+1 (operands prefetched)
        f32x4 e2[4];
        #pragma unroll
        for (int nt = 0; nt < 4; nt++)
            e2[nt] = __builtin_amdgcn_mfma_f32_16x16x32_bf16(aq, bk[nt], lnsC, 0, 0, 0);
        // prefetch aq/lns for ic+2
        const size_t ipf = (ic < 30) ? (i0 + 256) : i0;
        aq = *(const bf16x8*)(qrow + ipf * 64);
        lnsC = *(const f32x4*)(lrow + ipf);
        // finish E: exp2 + pack + write P(ic+1) — lgkm drains during O-phase
        write_p(plds[cur ^ 1], e2, w, lid, quad, xkey);
        // O-phase on buf cur; after last use of av[*][h], reload it in place
        #pragma unroll
        for (int h = 0; h < 4; h++) {
            bf16x8 bp[4];
            #pragma unroll
            for (int nt = 0; nt < 4; nt++)
                bp[nt] = *(const bf16x8*)&plds[cur][nt * 16 + lid][((4 * h + quad) ^ xkey) * 8];
            #pragma unroll
            for (int mt = 0; mt < 2; mt++)
                #pragma unroll
                for (int nt = 0; nt < 4; nt++)
                    acc[mt][nt] = __builtin_amdgcn_mfma_f32_16x16x32_bf16(av[mt * 4 + h], bp[nt], acc[mt][nt], 0, 0, 0);
            // in-place reload for next iter (WAR on regs already read by MFMA)
            #pragma unroll
            for (int mt = 0; mt < 2; mt++)
                av[mt * 4 + h] = *(const bf16x8*)(vrow + (size_t)mt * 16 * LL + (i0 + 128) + h * 32);
        }
        __syncthreads();
    }
    // ---- final O-phase: ic=31, buf 1 ----
    #pragma unroll
    for (int h = 0; h < 4; h++) {
        bf16x8 bp[4];
        #pragma unroll
        for (int nt = 0; nt < 4; nt++)
            bp[nt] = *(const bf16x8*)&plds[1][nt * 16 + lid][((4 * h + quad) ^ xkey) * 8];
        #pragma unroll
        for (int mt = 0; mt < 2; mt++)
            #pragma unroll
            for (int nt = 0; nt < 4; nt++)
                acc[mt][nt] = __builtin_amdgcn_mfma_f32_16x16x32_bf16(av[mt * 4 + h], bp[nt], acc[mt][nt], 0, 0, 0);
    }
    __syncthreads();   // all P reads done; reuse LDS as olds

    // ---- epilogue: o-tile -> olds[j][v] ----
    #pragma unroll
    for (int mt = 0; mt < 2; mt++)
        #pragma unroll
        for (int nt = 0; nt < 4; nt++) {
            ushort4 s;
            s.x = f2bf(acc[mt][nt][0]); s.y = f2bf(acc[mt][nt][1]);
            s.z = f2bf(acc[mt][nt][2]); s.w = f2bf(acc[mt][nt][3]);
            *(ushort4*)&olds[nt * 16 + lid][w * 32 + mt * 16 + quad * 4] = s;
        }
    __syncthreads();
    // out rows [w*32, w*32+32) x 64 l
    f32x4 oacc[2][4];
    #pragma unroll
    for (int mt = 0; mt < 2; mt++)
        #pragma unroll
        for (int nt = 0; nt < 4; nt++) oacc[mt][nt] = fzero;
    for (int k0 = 0; k0 < 256; k0 += 32) {
        bf16x8 bo[4];
        #pragma unroll
        for (int nt = 0; nt < 4; nt++)
            bo[nt] = *(const bf16x8*)&olds[nt * 16 + lid][k0 + quad * 8];
        #pragma unroll
        for (int mt = 0; mt < 2; mt++) {
            const bf16x8 wa = *(const bf16x8*)&Wob[(w * 32 + mt * 16 + lid) * 256 + k0 + quad * 8];
            #pragma unroll
            for (int nt = 0; nt < 4; nt++)
                oacc[mt][nt] = __builtin_amdgcn_mfma_f32_16x16x32_bf16(wa, bo[nt], oacc[mt][nt], 0, 0, 0);
        }
    }
    const float g = *gp;
    #pragma unroll
    for (int mt = 0; mt < 2; mt++)
        #pragma unroll
        for (int nt = 0; nt < 4; nt++)
            #pragma unroll
            for (int reg = 0; reg < 4; reg++) {
                const int r = w * 32 + mt * 16 + quad * 4 + reg;
                out[((size_t)n * CIN + r) * LL + j0 + nt * 16 + lid] = g * oacc[mt][nt][reg];
            }
}

extern "C" void kernel_launch(void* const* d_in, const int* in_sizes, int n_in,
                              void* d_out, int out_size, void* d_ws, size_t ws_size,
                              hipStream_t stream) {
    const float* x     = (const float*)d_in[0];
    const float* Wq    = (const float*)d_in[1];
    const float* Wk    = (const float*)d_in[2];
    const float* Wv    = (const float*)d_in[3];
    const float* Wo    = (const float*)d_in[4];
    const float* gamma = (const float*)d_in[5];

    unsigned short* qkt = (unsigned short*)d_ws;              // 4 MB
    unsigned short* v   = qkt + (size_t)NB * LL * 64;         // 16 MB
    unsigned short* Wb  = v + (size_t)NB * CV * LL;           // 160 KB
    unsigned short* Wob = Wb + 320 * 256;                     // 128 KB
    float* lns          = (float*)(Wob + 256 * 256);          // 128 KB
    float* out = (float*)d_out;

    k_wcast  <<<dim3(576),   256, 0, stream>>>(Wq, Wk, Wv, Wo, Wb, Wob);
    k_qkv3   <<<dim3(64, 8), 512, 0, stream>>>(x, Wb, qkt, v);
    k_rowsum3<<<dim3(64, 8), 512, 0, stream>>>(qkt, lns);
    k_attn6  <<<dim3(512),   512, 0, stream>>>(qkt, v, lns, Wob, gamma, out);
}